// Round 9
// baseline (20693.391 us; speedup 1.0000x reference)
//
#include <hip/hip_runtime.h>

// LSTM_65859028517106 — round 9: r8 (16 blocks x 128 gate-rows/layer, W
// fragment-major streamed via cached loads, h via IC-bypass) with the
// cross-wave LDS race fixed: epilogue writeback is wave-local (each wave
// reads only stage rows it wrote, like r4).

typedef short s16x8 __attribute__((ext_vector_type(8)));
typedef float f32x4 __attribute__((ext_vector_type(4)));

#define NB   128
#define TT   1024
#define HID2 512
#define RING 8
#define NBH  (NB * HID2)

__device__ __forceinline__ unsigned short f2bf(float f) {
  union { float f; unsigned int u; } c; c.f = f;
  return (unsigned short)((c.u + 0x7fffu + ((c.u >> 16) & 1u)) >> 16);
}
__device__ __forceinline__ float sigm(float x) { return 1.0f / (1.0f + __expf(-x)); }
__device__ __forceinline__ float tanhfast(float x) {
  x = fminf(fmaxf(x, -15.0f), 15.0f);
  const float e = __expf(2.0f * x);
  return (e - 1.0f) / (e + 1.0f);
}

// W -> fragment-major bf16: frag(wgi, kit, mf) is 1KB, lane-major; value at
// [lane*8+e] = W[wgi*128 + mf*16 + (lane&15)][kit*32 + (lane>>4)*8 + e].
__global__ void convW(const float* __restrict__ Wih, const float* __restrict__ Whh,
                      const float* __restrict__ bih, const float* __restrict__ bhh,
                      unsigned short* __restrict__ Wd, float* __restrict__ biasd,
                      const int Kih, const int Khh) {
  const int K = Kih + Khh;
  const int NK = K >> 5;
  const int total = 2048 * K;
  for (int idx = blockIdx.x * blockDim.x + threadIdx.x; idx < total;
       idx += gridDim.x * blockDim.x) {
    const int rp = idx / K;
    const int cc = idx - rp * K;
    const int g = rp & 3, u = rp >> 2;
    const int ro = g * 512 + u;
    const float v = (cc < Kih) ? Wih[ro * Kih + cc] : Whh[ro * Khh + (cc - Kih)];
    const int wgi = rp >> 7, mfi = (rp >> 4) & 7, l15r = rp & 15;
    const int kit = cc >> 5, l4c = (cc >> 3) & 3, e = cc & 7;
    const int lane = l4c * 16 + l15r;
    Wd[((((size_t)(wgi * NK + kit)) * 8 + mfi) << 9) + lane * 8 + e] = f2bf(v);
    if (cc == 0) biasd[rp] = bih[ro] + bhh[ro];
  }
}

__global__ void convO(const float* __restrict__ Wout, unsigned short* __restrict__ Wd) {
  for (int idx = blockIdx.x * blockDim.x + threadIdx.x; idx < 128 * 512;
       idx += gridDim.x * blockDim.x)
    Wd[idx] = f2bf(Wout[idx]);
}

// ---- IC-bypass (system coherent) B-loads / stores ----
#define GLD2(D0, D1, B0, B1, OFF)                                         \
  asm volatile("global_load_dwordx4 %0, %2, off offset:" OFF " sc0 sc1\n\t" \
               "global_load_dwordx4 %1, %3, off offset:" OFF " sc0 sc1"   \
               : "=v"(D0), "=v"(D1) : "v"(B0), "v"(B1));
#define GLD1(D, B, OFF)                                                   \
  asm volatile("global_load_dwordx4 %0, %1, off offset:" OFF " sc0 sc1"   \
               : "=v"(D) : "v"(B));
// ---- cached A-loads (read-only W: coherence-free) ----
#define GLDA(D, P, OFF)                                                   \
  asm volatile("global_load_dwordx4 %0, %1, off offset:" OFF              \
               : "=v"(D) : "v"(P));
#define BW1(D, VM)                                                        \
  asm volatile("s_waitcnt vmcnt(" VM ")" : "+v"(D)::"memory");

#define MFM(A, B, C) __builtin_amdgcn_mfma_f32_16x16x32_bf16(A, B, C, 0, 0, 0)

#define ISSUE_A8(S, J)                                                          \
  { const unsigned short* ap0 = wf + (J) * 4096;                                \
    const unsigned short* ap1 = ap0 + 2048;                                     \
    GLDA(ar[S][0], ap0, "0")    GLDA(ar[S][1], ap0, "1024")                     \
    GLDA(ar[S][2], ap0, "2048") GLDA(ar[S][3], ap0, "3072")                     \
    GLDA(ar[S][4], ap1, "0")    GLDA(ar[S][5], ap1, "1024")                     \
    GLDA(ar[S][6], ap1, "2048") GLDA(ar[S][7], ap1, "3072") }
#define ISSUE_AB(S, J, P0, P1, OFF)                                             \
  { GLD2(br[S][0], br[S][1], P0, P1, OFF) ISSUE_A8(S, J) }

#define KW10(S, VM)                                                             \
  asm volatile("s_waitcnt vmcnt(" VM ")"                                        \
    : "+v"(ar[S][0]), "+v"(ar[S][1]), "+v"(ar[S][2]), "+v"(ar[S][3]),           \
      "+v"(ar[S][4]), "+v"(ar[S][5]), "+v"(ar[S][6]), "+v"(ar[S][7]),           \
      "+v"(br[S][0]), "+v"(br[S][1]) :: "memory");
#define KW8(S, VM)                                                              \
  asm volatile("s_waitcnt vmcnt(" VM ")"                                        \
    : "+v"(ar[S][0]), "+v"(ar[S][1]), "+v"(ar[S][2]), "+v"(ar[S][3]),           \
      "+v"(ar[S][4]), "+v"(ar[S][5]), "+v"(ar[S][6]), "+v"(ar[S][7]) :: "memory");

#define KMFMA(S, B0, B1)                                                        \
  acc[0][0] = MFM(ar[S][0], B0, acc[0][0]); acc[0][1] = MFM(ar[S][0], B1, acc[0][1]); \
  acc[1][0] = MFM(ar[S][1], B0, acc[1][0]); acc[1][1] = MFM(ar[S][1], B1, acc[1][1]); \
  acc[2][0] = MFM(ar[S][2], B0, acc[2][0]); acc[2][1] = MFM(ar[S][2], B1, acc[2][1]); \
  acc[3][0] = MFM(ar[S][3], B0, acc[3][0]); acc[3][1] = MFM(ar[S][3], B1, acc[3][1]); \
  acc[4][0] = MFM(ar[S][4], B0, acc[4][0]); acc[4][1] = MFM(ar[S][4], B1, acc[4][1]); \
  acc[5][0] = MFM(ar[S][5], B0, acc[5][0]); acc[5][1] = MFM(ar[S][5], B1, acc[5][1]); \
  acc[6][0] = MFM(ar[S][6], B0, acc[6][0]); acc[6][1] = MFM(ar[S][6], B1, acc[6][1]); \
  acc[7][0] = MFM(ar[S][7], B0, acc[7][0]); acc[7][1] = MFM(ar[S][7], B1, acc[7][1]);

#define STEP(S, JN, VM, P0, P1, OFF)                                            \
  { KW10(S, VM); KMFMA(S, br[S][0], br[S][1]); ISSUE_AB(S, JN, P0, P1, OFF) }
#define TSTEP(S, VM)                                                            \
  { KW10(S, VM); KMFMA(S, br[S][0], br[S][1]); }
#define XSTEP(S, KX, VM, JN, P0, P1, OFF)                                       \
  { KW8(S, VM); KMFMA(S, xb[KX][0], xb[KX][1]); ISSUE_AB(S, JN, P0, P1, OFF) }

#define FLG(L, T) (flags + ((size_t)((L) * TT + (T)) << 4))

__global__ __launch_bounds__(256, 1) void lstm_s16(
    const float* __restrict__ x,
    const unsigned short* __restrict__ W0, const unsigned short* __restrict__ W1,
    const unsigned short* __restrict__ W2, const unsigned short* __restrict__ W3,
    const unsigned short* __restrict__ W4,
    const unsigned short* __restrict__ Woutb,
    const float* __restrict__ bias,
    unsigned short* __restrict__ hring,   // [5][RING][128][512]
    unsigned int* __restrict__ flags,     // [6][TT][16]
    const float* __restrict__ boutp,
    float* __restrict__ outp)
{
  extern __shared__ char smem[];
  const int tid = threadIdx.x;
  const int lane = tid & 63;
  const int w = tid >> 6;
  const int l15 = lane & 15;
  const int l4 = lane >> 4;
  const int bid = blockIdx.x;

  auto pollAll = [&](const unsigned int* pa) {
    for (;;) {
      unsigned int v;
      asm volatile("global_load_dword %0, %1, off sc0 sc1\n\ts_waitcnt vmcnt(0)"
                   : "=v"(v) : "v"(pa) : "memory");
      if (__all(v != 0)) break;
      __builtin_amdgcn_s_sleep(1);
    }
  };

  if (bid < 80) {
    const int l = bid >> 4;        // 16 blocks per layer
    const int wgi = bid & 15;
    const int K = (l == 0) ? 640 : 1024;
    const int NK = K >> 5;
    const unsigned short* Wg = (l == 0) ? W0 : (l == 1) ? W1 : (l == 2) ? W2
                              : (l == 3) ? W3 : W4;
    const unsigned short* wf = Wg + ((size_t)wgi * NK * 8) * 512 + lane * 8;
    const int row0 = wgi * 128;

    float4 b4m[8];
    #pragma unroll
    for (int mf = 0; mf < 8; ++mf)
      b4m[mf] = *(const float4*)(bias + l * 2048 + row0 + mf * 16 + l4 * 4);

    float c_reg[8][2] = {};
    s16x8 ar[4][8];
    s16x8 br[4][2];
    unsigned short* stage = (unsigned short*)smem;   // [128 b][32 u] bf16 = 8KB

    for (int t = 0; t < TT; ++t) {
      const unsigned short* hin =
          (l > 0) ? hring + (size_t)((l - 1) * RING + (t & 7)) * NBH : nullptr;
      const unsigned short* hown = hring + (size_t)(l * RING + ((t + 7) & 7)) * NBH;
      unsigned short* hout = hring + (size_t)(l * RING + (t & 7)) * NBH;

      f32x4 acc[8][2] = {};
      s16x8 xb[4][2];

      if (l == 0) {
        #pragma unroll
        for (int kx = 0; kx < 4; ++kx)
          #pragma unroll
          for (int nf = 0; nf < 2; ++nf) {
            const float* xs = x + ((size_t)(w * 32 + nf * 16 + l15) * TT + t) * 128
                              + kx * 32 + l4 * 8;
            const float4 v0 = *(const float4*)xs;
            const float4 v1 = *(const float4*)(xs + 4);
            union { s16x8 v; unsigned short a[8]; } pk;
            pk.a[0] = f2bf(v0.x); pk.a[1] = f2bf(v0.y); pk.a[2] = f2bf(v0.z); pk.a[3] = f2bf(v0.w);
            pk.a[4] = f2bf(v1.x); pk.a[5] = f2bf(v1.y); pk.a[6] = f2bf(v1.z); pk.a[7] = f2bf(v1.w);
            xb[kx][nf] = pk.v;
          }
      }

      // fused poll: lanes 0..31 self(t-1), 32..63 prev(t)
      if (t > 0 || l > 0) {
        const unsigned int* pa;
        if (lane < 32)
          pa = (t > 0) ? FLG(l, t - 1) + (lane & 15) : FLG(l - 1, t) + (lane & 15);
        else
          pa = (l > 0) ? FLG(l - 1, t) + (lane & 15) : FLG(l, t - 1) + (lane & 15);
        pollAll(pa);
      }
      if (t >= RING) {
        const unsigned int* pa = (l < 4) ? FLG(l + 1, t - RING) + (lane & 15)
                                         : FLG(5, t - RING) + (lane & 7);
        pollAll(pa);
      }

      const unsigned short* pb0 = hown + (size_t)(w * 32 + l15) * HID2 + l4 * 8;
      const unsigned short* pb1 = pb0 + 16 * HID2;

      if (l == 0) {
        // bundles: 0..3 A-only (x in regs), 4..19 {B from hown, A}
        ISSUE_A8(0, 0) ISSUE_A8(1, 1) ISSUE_A8(2, 2) ISSUE_A8(3, 3)
        XSTEP(0, 0, "24", 4, pb0, pb1, "0")
        XSTEP(1, 1, "26", 5, pb0, pb1, "64")
        XSTEP(2, 2, "28", 6, pb0, pb1, "128")
        XSTEP(3, 3, "30", 7, pb0, pb1, "192")
        STEP(0, 8,  "30", pb0, pb1, "256")  STEP(1, 9,  "30", pb0, pb1, "320")
        STEP(2, 10, "30", pb0, pb1, "384")  STEP(3, 11, "30", pb0, pb1, "448")
        STEP(0, 12, "30", pb0, pb1, "512")  STEP(1, 13, "30", pb0, pb1, "576")
        STEP(2, 14, "30", pb0, pb1, "640")  STEP(3, 15, "30", pb0, pb1, "704")
        STEP(0, 16, "30", pb0, pb1, "768")  STEP(1, 17, "30", pb0, pb1, "832")
        STEP(2, 18, "30", pb0, pb1, "896")  STEP(3, 19, "30", pb0, pb1, "960")
        TSTEP(0, "30") TSTEP(1, "20") TSTEP(2, "10") TSTEP(3, "0")
      } else {
        const unsigned short* qb0 = hin + (size_t)(w * 32 + l15) * HID2 + l4 * 8;
        const unsigned short* qb1 = qb0 + 16 * HID2;
        // bundles 0..15 {B from hin}, 16..31 {B from hown}
        ISSUE_AB(0, 0, qb0, qb1, "0")   ISSUE_AB(1, 1, qb0, qb1, "64")
        ISSUE_AB(2, 2, qb0, qb1, "128") ISSUE_AB(3, 3, qb0, qb1, "192")
        STEP(0, 4,  "30", qb0, qb1, "256")  STEP(1, 5,  "30", qb0, qb1, "320")
        STEP(2, 6,  "30", qb0, qb1, "384")  STEP(3, 7,  "30", qb0, qb1, "448")
        STEP(0, 8,  "30", qb0, qb1, "512")  STEP(1, 9,  "30", qb0, qb1, "576")
        STEP(2, 10, "30", qb0, qb1, "640")  STEP(3, 11, "30", qb0, qb1, "704")
        STEP(0, 12, "30", qb0, qb1, "768")  STEP(1, 13, "30", qb0, qb1, "832")
        STEP(2, 14, "30", qb0, qb1, "896")  STEP(3, 15, "30", qb0, qb1, "960")
        STEP(0, 16, "30", pb0, pb1, "0")    STEP(1, 17, "30", pb0, pb1, "64")
        STEP(2, 18, "30", pb0, pb1, "128")  STEP(3, 19, "30", pb0, pb1, "192")
        STEP(0, 20, "30", pb0, pb1, "256")  STEP(1, 21, "30", pb0, pb1, "320")
        STEP(2, 22, "30", pb0, pb1, "384")  STEP(3, 23, "30", pb0, pb1, "448")
        STEP(0, 24, "30", pb0, pb1, "512")  STEP(1, 25, "30", pb0, pb1, "576")
        STEP(2, 26, "30", pb0, pb1, "640")  STEP(3, 27, "30", pb0, pb1, "704")
        STEP(0, 28, "30", pb0, pb1, "768")  STEP(1, 29, "30", pb0, pb1, "832")
        STEP(2, 30, "30", pb0, pb1, "896")  STEP(3, 31, "30", pb0, pb1, "960")
        TSTEP(0, "30") TSTEP(1, "20") TSTEP(2, "10") TSTEP(3, "0")
      }

      // epilogue: gates -> c (regs); h -> LDS stage -> coalesced sc0sc1 stores.
      // WAVE-LOCAL writeback: each wave reads only the 32 stage rows it wrote.
      #pragma unroll
      for (int mf = 0; mf < 8; ++mf) {
        #pragma unroll
        for (int nf = 0; nf < 2; ++nf) {
          const float gi = acc[mf][nf][0] + b4m[mf].x;
          const float gf = acc[mf][nf][1] + b4m[mf].y;
          const float gg = acc[mf][nf][2] + b4m[mf].z;
          const float go = acc[mf][nf][3] + b4m[mf].w;
          const float cn = sigm(gf) * c_reg[mf][nf] + sigm(gi) * tanhfast(gg);
          c_reg[mf][nf] = cn;
          stage[(w * 32 + nf * 16 + l15) * 32 + mf * 4 + l4] =
              f2bf(sigm(go) * tanhfast(cn));
        }
      }
      asm volatile("s_waitcnt lgkmcnt(0)" ::: "memory");
      __builtin_amdgcn_sched_barrier(0);
      {
        const int row = w * 32 + (lane >> 1);     // wave-local row
        const int q0 = (lane & 1) * 2;            // chunks q0, q0+1
        const s16x8 h0 = *reinterpret_cast<const s16x8*>(stage + row * 32 + q0 * 8);
        const s16x8 h1 = *reinterpret_cast<const s16x8*>(stage + row * 32 + q0 * 8 + 8);
        const unsigned short* ha0 = hout + (size_t)row * HID2 + wgi * 32 + q0 * 8;
        asm volatile("global_store_dwordx4 %0, %2, off sc0 sc1\n\t"
                     "global_store_dwordx4 %1, %3, off offset:16 sc0 sc1"
                     :: "v"(ha0), "v"(ha0), "v"(h0), "v"(h1) : "memory");
      }
      asm volatile("s_waitcnt vmcnt(0)" ::: "memory");
      __syncthreads();
      if (tid == 0) {
        const unsigned int* fa = FLG(l, t) + wgi;
        asm volatile("global_store_dword %0, %1, off sc0 sc1" :: "v"(fa), "v"(1u) : "memory");
      }
    }
  } else if (bid < 88) {
    // ---------------- projection (r4 path; 16-flag polls) ----------------
    const int wgp = bid - 80;
    const int b0 = wgp * 16;
    for (int mf = 0; mf < 2; ++mf)
      for (int kit = 0; kit < 16; ++kit) {
        const s16x8 v = *reinterpret_cast<const s16x8*>(
            Woutb + (size_t)(w * 32 + mf * 16 + l15) * 512 + kit * 32 + l4 * 8);
        *reinterpret_cast<s16x8*>(smem + (((w * 2 + mf) * 16 + kit) << 10) + lane * 16) = v;
      }
    __syncthreads();
    float4 bo[2];
    #pragma unroll
    for (int mf = 0; mf < 2; ++mf)
      bo[mf] = *(const float4*)(boutp + w * 32 + mf * 16 + l4 * 4);

    s16x8 brp[16];
    for (int t = 0; t < TT; ++t) {
      pollAll(FLG(4, t) + (lane & 15));
      const unsigned short* h4 = hring + (size_t)(4 * RING + (t & 7)) * NBH;
      const unsigned short* hb = h4 + (size_t)(b0 + l15) * HID2 + l4 * 8;
      GLD1(brp[0], hb, "0")    GLD1(brp[1], hb, "64")   GLD1(brp[2], hb, "128")  GLD1(brp[3], hb, "192")
      GLD1(brp[4], hb, "256")  GLD1(brp[5], hb, "320")  GLD1(brp[6], hb, "384")  GLD1(brp[7], hb, "448")
      GLD1(brp[8], hb, "512")  GLD1(brp[9], hb, "576")  GLD1(brp[10], hb, "640") GLD1(brp[11], hb, "704")
      GLD1(brp[12], hb, "768") GLD1(brp[13], hb, "832") GLD1(brp[14], hb, "896") GLD1(brp[15], hb, "960")
      f32x4 acc2[2] = {};
      #define PCON(Q, VM)                                                        \
        {                                                                        \
          BW1(brp[Q], VM);                                                       \
          const s16x8 a0 = *reinterpret_cast<const s16x8*>(                      \
              smem + (((w * 2 + 0) * 16 + Q) << 10) + lane * 16);                \
          const s16x8 a1 = *reinterpret_cast<const s16x8*>(                      \
              smem + (((w * 2 + 1) * 16 + Q) << 10) + lane * 16);                \
          acc2[0] = MFM(a0, brp[Q], acc2[0]);                                    \
          acc2[1] = MFM(a1, brp[Q], acc2[1]);                                    \
        }
      PCON(0, "15")  PCON(1, "14")  PCON(2, "13")  PCON(3, "12")
      PCON(4, "11")  PCON(5, "10")  PCON(6, "9")   PCON(7, "8")
      PCON(8, "7")   PCON(9, "6")   PCON(10, "5")  PCON(11, "4")
      PCON(12, "3")  PCON(13, "2")  PCON(14, "1")  PCON(15, "0")
      #pragma unroll
      for (int mf = 0; mf < 2; ++mf) {
        const int d0 = w * 32 + mf * 16 + l4 * 4;
        float4 r;
        r.x = acc2[mf][0] + bo[mf].x;
        r.y = acc2[mf][1] + bo[mf].y;
        r.z = acc2[mf][2] + bo[mf].z;
        r.w = acc2[mf][3] + bo[mf].w;
        *(float4*)(outp + ((size_t)(b0 + l15) * TT + t) * 128 + d0) = r;
      }
      asm volatile("s_waitcnt vmcnt(0)" ::: "memory");
      __syncthreads();
      if (tid == 0) {
        const unsigned int* fa = FLG(5, t) + wgp;
        asm volatile("global_store_dword %0, %1, off sc0 sc1" :: "v"(fa), "v"(1u) : "memory");
      }
    }
  }
}

extern "C" void kernel_launch(void* const* d_in, const int* in_sizes, int n_in,
                              void* d_out, int out_size, void* d_ws, size_t ws_size,
                              hipStream_t stream) {
  (void)in_sizes; (void)n_in; (void)out_size; (void)ws_size;
  const float* x     = (const float*)d_in[0];
  const float* Wih1  = (const float*)d_in[1];
  const float* Whh1  = (const float*)d_in[2];
  const float* bih1  = (const float*)d_in[3];
  const float* bhh1  = (const float*)d_in[4];
  const float* Wih_r = (const float*)d_in[5];
  const float* Whh_r = (const float*)d_in[6];
  const float* bih_r = (const float*)d_in[7];
  const float* bhh_r = (const float*)d_in[8];
  const float* Wout  = (const float*)d_in[9];
  const float* boutp = (const float*)d_in[10];

  char* ws = (char*)d_ws;
  const size_t o_W0   = 0;
  const size_t o_W1   = o_W0 + 2048ull * 640 * 2;
  const size_t o_W2   = o_W1 + 2048ull * 1024 * 2;
  const size_t o_W3   = o_W2 + 2048ull * 1024 * 2;
  const size_t o_W4   = o_W3 + 2048ull * 1024 * 2;
  const size_t o_Wout = o_W4 + 2048ull * 1024 * 2;
  const size_t o_bias = o_Wout + 128ull * 512 * 2;
  const size_t o_ring = o_bias + 5ull * 2048 * 4;
  const size_t o_flag = o_ring + 5ull * RING * NBH * 2;
  const size_t o_end  = o_flag + 6ull * TT * 16 * 4;

  unsigned short* W0b  = (unsigned short*)(ws + o_W0);
  unsigned short* W1b  = (unsigned short*)(ws + o_W1);
  unsigned short* W2b  = (unsigned short*)(ws + o_W2);
  unsigned short* W3b  = (unsigned short*)(ws + o_W3);
  unsigned short* W4b  = (unsigned short*)(ws + o_W4);
  unsigned short* Wob  = (unsigned short*)(ws + o_Wout);
  float*          bias = (float*)(ws + o_bias);
  unsigned short* hrg  = (unsigned short*)(ws + o_ring);
  unsigned int*   flg  = (unsigned int*)(ws + o_flag);

  hipMemsetAsync(ws + o_ring, 0, o_end - o_ring, stream);

  convW<<<1024, 256, 0, stream>>>(Wih1, Whh1, bih1, bhh1, W0b, bias, 128, 512);
  for (int l = 1; l <= 4; ++l) {
    unsigned short* Wd = (l == 1) ? W1b : (l == 2) ? W2b : (l == 3) ? W3b : W4b;
    convW<<<1024, 256, 0, stream>>>(Wih_r + (size_t)(l - 1) * 2048 * 512,
                                    Whh_r + (size_t)(l - 1) * 2048 * 512,
                                    bih_r + (size_t)(l - 1) * 2048,
                                    bhh_r + (size_t)(l - 1) * 2048,
                                    Wd, bias + l * 2048, 512, 512);
  }
  convO<<<64, 256, 0, stream>>>(Wout, Wob);

  hipFuncSetAttribute((const void*)lstm_s16,
                      hipFuncAttributeMaxDynamicSharedMemorySize, 160 * 1024);

  lstm_s16<<<88, 256, 131072, stream>>>(x, W0b, W1b, W2b, W3b, W4b, Wob,
                                        bias, hrg, flg, boutp, (float*)d_out);
}

// Round 10
// 12243.805 us; speedup vs baseline: 1.6901x; 1.6901x over previous
//
#include <hip/hip_runtime.h>

// LSTM_65859028517106 — round 10: r4/r5-fallback kernel + 4x-replicated
// h ring & flags (consumer wgi reads replica wgi&3) to de-serialize IC
// same-line contention; RING=16 with 1-in-4-step back-pressure polls.
// Runtime nrep/ring params; falls back to exact r4 shape if ws is small.

typedef short s16x8 __attribute__((ext_vector_type(8)));
typedef float f32x4 __attribute__((ext_vector_type(4)));

#define NB   128
#define TT   1024
#define HID2 512
#define NBH  (NB * HID2)
#define STAGE_OFF (128 * 1024)
#define FREP (6 * TT * 32)          // flag words per replica

__device__ __forceinline__ unsigned short f2bf(float f) {
  union { float f; unsigned int u; } c; c.f = f;
  return (unsigned short)((c.u + 0x7fffu + ((c.u >> 16) & 1u)) >> 16);
}
__device__ __forceinline__ float sigm(float x) { return 1.0f / (1.0f + __expf(-x)); }
__device__ __forceinline__ float tanhfast(float x) {
  x = fminf(fmaxf(x, -15.0f), 15.0f);
  const float e = __expf(2.0f * x);
  return (e - 1.0f) / (e + 1.0f);
}

__global__ void convW(const float* __restrict__ Wih, const float* __restrict__ Whh,
                      const float* __restrict__ bih, const float* __restrict__ bhh,
                      unsigned short* __restrict__ Wd, float* __restrict__ biasd,
                      const int Kih, const int Khh) {
  const int K = Kih + Khh;
  const int total = 2048 * K;
  for (int idx = blockIdx.x * blockDim.x + threadIdx.x; idx < total;
       idx += gridDim.x * blockDim.x) {
    const int rp = idx / K;
    const int cc = idx - rp * K;
    const int g = rp & 3, u = rp >> 2;
    const int ro = g * 512 + u;
    const float v = (cc < Kih) ? Wih[ro * Kih + cc] : Whh[ro * Khh + (cc - Kih)];
    Wd[idx] = f2bf(v);
    if (cc == 0) biasd[rp] = bih[ro] + bhh[ro];
  }
}

__global__ void convO(const float* __restrict__ Wout, unsigned short* __restrict__ Wd) {
  for (int idx = blockIdx.x * blockDim.x + threadIdx.x; idx < 128 * 512;
       idx += gridDim.x * blockDim.x)
    Wd[idx] = f2bf(Wout[idx]);
}

#define GLD2(D0, D1, B0, B1, OFF)                                         \
  asm volatile("global_load_dwordx4 %0, %2, off offset:" OFF " sc0 sc1\n\t" \
               "global_load_dwordx4 %1, %3, off offset:" OFF " sc0 sc1"   \
               : "=v"(D0), "=v"(D1) : "v"(B0), "v"(B1));
#define GLD1(D, B, OFF)                                                   \
  asm volatile("global_load_dwordx4 %0, %1, off offset:" OFF " sc0 sc1"   \
               : "=v"(D) : "v"(B));
#define BWAIT(D0, D1, VM)                                                 \
  asm volatile("s_waitcnt vmcnt(" VM ")" : "+v"(D0), "+v"(D1)::"memory");
#define BW1(D, VM)                                                        \
  asm volatile("s_waitcnt vmcnt(" VM ")" : "+v"(D)::"memory");

#define MFM(A, B, C) __builtin_amdgcn_mfma_f32_16x16x32_bf16(A, B, C, 0, 0, 0)
#define LDSA(MFi, AK) \
  (*reinterpret_cast<const s16x8*>(smem + (((MFi) * nkit + (AK)) << 10) + lane * 16))
#define CONSUME(SLOT, AK, VM)                                                   \
  {                                                                             \
    BWAIT(bq[SLOT][0], bq[SLOT][1], VM);                                        \
    const s16x8 af0 = LDSA(0, AK), af1 = LDSA(1, AK), af2 = LDSA(2, AK),        \
                af3 = LDSA(3, AK);                                              \
    acc[0][0] = MFM(af0, bq[SLOT][0], acc[0][0]);                               \
    acc[0][1] = MFM(af0, bq[SLOT][1], acc[0][1]);                               \
    acc[1][0] = MFM(af1, bq[SLOT][0], acc[1][0]);                               \
    acc[1][1] = MFM(af1, bq[SLOT][1], acc[1][1]);                               \
    acc[2][0] = MFM(af2, bq[SLOT][0], acc[2][0]);                               \
    acc[2][1] = MFM(af2, bq[SLOT][1], acc[2][1]);                               \
    acc[3][0] = MFM(af3, bq[SLOT][0], acc[3][0]);                               \
    acc[3][1] = MFM(af3, bq[SLOT][1], acc[3][1]);                               \
  }

__global__ __launch_bounds__(256, 1) void lstm_rep(
    const float* __restrict__ x,
    const unsigned short* __restrict__ W0, const unsigned short* __restrict__ W1,
    const unsigned short* __restrict__ W2, const unsigned short* __restrict__ W3,
    const unsigned short* __restrict__ W4,
    const unsigned short* __restrict__ Woutb,
    const float* __restrict__ bias,
    unsigned short* __restrict__ hring,   // [nrep][5][nring][128][512]
    unsigned int* __restrict__ flags,     // [nrep][6][TT][32]
    const float* __restrict__ boutp,
    float* __restrict__ outp,
    const int nrepm,        // replica mask (3 or 0)
    const int nring,        // ring slots (16 or 8)
    const int ringm,        // nring-1
    const size_t hrepsz)    // elems per h replica = 5*nring*NBH
{
  extern __shared__ char smem[];
  const int tid = threadIdx.x;
  const int lane = tid & 63;
  const int w = tid >> 6;
  const int l15 = lane & 15;
  const int l4 = lane >> 4;
  const int bid = blockIdx.x;

  auto pollAll = [&](const unsigned int* pa) {
    for (;;) {
      unsigned int v;
      asm volatile("global_load_dword %0, %1, off sc0 sc1\n\ts_waitcnt vmcnt(0)"
                   : "=v"(v) : "v"(pa) : "memory");
      if (__all(v != 0)) break;
      __builtin_amdgcn_s_sleep(1);
    }
  };

  if (bid < 160) {
    const int l = bid >> 5;
    const int wgi = bid & 31;
    const int rep = wgi & nrepm;
    const unsigned int* fb = flags + (size_t)rep * FREP;   // consumer flag base
    #define FLGC(L, T) (fb + ((size_t)((L) * TT + (T)) << 5))
    const int K = (l == 0) ? 640 : 1024;
    const int nkit = K >> 5;
    const unsigned short* Wg = (l == 0) ? W0 : (l == 1) ? W1 : (l == 2) ? W2
                              : (l == 3) ? W3 : W4;
    const int row0 = wgi * 64;

    for (int mf = 0; mf < 4; ++mf)
      for (int kit = w; kit < nkit; kit += 4) {
        const s16x8 v = *reinterpret_cast<const s16x8*>(
            Wg + (size_t)(row0 + mf * 16 + l15) * K + kit * 32 + l4 * 8);
        *reinterpret_cast<s16x8*>(smem + ((mf * nkit + kit) << 10) + lane * 16) = v;
      }
    __syncthreads();

    float4 b4m[4];
    #pragma unroll
    for (int mf = 0; mf < 4; ++mf)
      b4m[mf] = *(const float4*)(bias + l * 2048 + row0 + mf * 16 + l4 * 4);

    float c_reg[4][2] = {};
    s16x8 bq[16][2];
    unsigned short* stage = (unsigned short*)(smem + STAGE_OFF);
    const int sb = w * 32 + (lane >> 1);
    const int sh = lane & 1;

    for (int t = 0; t < TT; ++t) {
      const int slotP = t & ringm, slotM = (t + ringm) & ringm;
      const unsigned short* hin = (l > 0)
          ? hring + (size_t)rep * hrepsz + (size_t)((l - 1) * nring + slotP) * NBH
          : nullptr;
      const unsigned short* hown =
          hring + (size_t)rep * hrepsz + (size_t)(l * nring + slotM) * NBH;

      f32x4 acc[4][2] = {};
      s16x8 xb[4][2];

      if (l == 0) {
        #pragma unroll
        for (int kx = 0; kx < 4; ++kx)
          #pragma unroll
          for (int nf = 0; nf < 2; ++nf) {
            const float* xs = x + ((size_t)(w * 32 + nf * 16 + l15) * TT + t) * 128
                              + kx * 32 + l4 * 8;
            const float4 v0 = *(const float4*)xs;
            const float4 v1 = *(const float4*)(xs + 4);
            union { s16x8 v; unsigned short a[8]; } pk;
            pk.a[0] = f2bf(v0.x); pk.a[1] = f2bf(v0.y); pk.a[2] = f2bf(v0.z); pk.a[3] = f2bf(v0.w);
            pk.a[4] = f2bf(v1.x); pk.a[5] = f2bf(v1.y); pk.a[6] = f2bf(v1.z); pk.a[7] = f2bf(v1.w);
            xb[kx][nf] = pk.v;
          }
      }

      // fused poll: lanes 0..31 self(t-1), lanes 32..63 prev(t)
      if (t > 0 || l > 0) {
        const unsigned int* pa;
        if (lane < 32)
          pa = (t > 0) ? FLGC(l, t - 1) + lane : FLGC(l - 1, t) + lane;
        else
          pa = (l > 0) ? FLGC(l - 1, t) + (lane - 32) : FLGC(l, t - 1) + (lane - 32);
        pollAll(pa);
      }
      // back-pressure: RING=16 -> poll 1-in-4 steps at slack 13; RING=8 -> every step
      if (ringm == 15) {
        if ((t & 3) == 0 && t >= 16) {
          const unsigned int* pa = (l < 4) ? FLGC(l + 1, t - 13) + (lane & 31)
                                           : FLGC(5, t - 13) + (lane & 7);
          pollAll(pa);
        }
      } else if (t >= 8) {
        const unsigned int* pa = (l < 4) ? FLGC(l + 1, t - 8) + (lane & 31)
                                         : FLGC(5, t - 8) + (lane & 7);
        pollAll(pa);
      }

      const unsigned short* pb0 = hown + (size_t)(w * 32 + l15) * HID2 + l4 * 8;
      const unsigned short* pb1 = pb0 + 16 * HID2;

      if (l == 0) {
        GLD2(bq[0][0], bq[0][1], pb0, pb1, "0")    GLD2(bq[1][0], bq[1][1], pb0, pb1, "64")
        GLD2(bq[2][0], bq[2][1], pb0, pb1, "128")  GLD2(bq[3][0], bq[3][1], pb0, pb1, "192")
        GLD2(bq[4][0], bq[4][1], pb0, pb1, "256")  GLD2(bq[5][0], bq[5][1], pb0, pb1, "320")
        GLD2(bq[6][0], bq[6][1], pb0, pb1, "384")  GLD2(bq[7][0], bq[7][1], pb0, pb1, "448")
        GLD2(bq[8][0], bq[8][1], pb0, pb1, "512")  GLD2(bq[9][0], bq[9][1], pb0, pb1, "576")
        GLD2(bq[10][0], bq[10][1], pb0, pb1, "640") GLD2(bq[11][0], bq[11][1], pb0, pb1, "704")
        GLD2(bq[12][0], bq[12][1], pb0, pb1, "768") GLD2(bq[13][0], bq[13][1], pb0, pb1, "832")
        GLD2(bq[14][0], bq[14][1], pb0, pb1, "896") GLD2(bq[15][0], bq[15][1], pb0, pb1, "960")
        #pragma unroll
        for (int kx = 0; kx < 4; ++kx) {
          const s16x8 a0 = LDSA(0, kx), a1 = LDSA(1, kx), a2 = LDSA(2, kx), a3 = LDSA(3, kx);
          acc[0][0] = MFM(a0, xb[kx][0], acc[0][0]); acc[0][1] = MFM(a0, xb[kx][1], acc[0][1]);
          acc[1][0] = MFM(a1, xb[kx][0], acc[1][0]); acc[1][1] = MFM(a1, xb[kx][1], acc[1][1]);
          acc[2][0] = MFM(a2, xb[kx][0], acc[2][0]); acc[2][1] = MFM(a2, xb[kx][1], acc[2][1]);
          acc[3][0] = MFM(a3, xb[kx][0], acc[3][0]); acc[3][1] = MFM(a3, xb[kx][1], acc[3][1]);
        }
        CONSUME(0, 4, "30")   CONSUME(1, 5, "28")   CONSUME(2, 6, "26")   CONSUME(3, 7, "24")
        CONSUME(4, 8, "22")   CONSUME(5, 9, "20")   CONSUME(6, 10, "18")  CONSUME(7, 11, "16")
        CONSUME(8, 12, "14")  CONSUME(9, 13, "12")  CONSUME(10, 14, "10") CONSUME(11, 15, "8")
        CONSUME(12, 16, "6")  CONSUME(13, 17, "4")  CONSUME(14, 18, "2")  CONSUME(15, 19, "0")
      } else {
        const unsigned short* qb0 = hin + (size_t)(w * 32 + l15) * HID2 + l4 * 8;
        const unsigned short* qb1 = qb0 + 16 * HID2;
        GLD2(bq[0][0], bq[0][1], pb0, pb1, "0")    GLD2(bq[1][0], bq[1][1], pb0, pb1, "64")
        GLD2(bq[2][0], bq[2][1], pb0, pb1, "128")  GLD2(bq[3][0], bq[3][1], pb0, pb1, "192")
        GLD2(bq[4][0], bq[4][1], pb0, pb1, "256")  GLD2(bq[5][0], bq[5][1], pb0, pb1, "320")
        GLD2(bq[6][0], bq[6][1], pb0, pb1, "384")  GLD2(bq[7][0], bq[7][1], pb0, pb1, "448")
        GLD2(bq[8][0], bq[8][1], pb0, pb1, "512")  GLD2(bq[9][0], bq[9][1], pb0, pb1, "576")
        GLD2(bq[10][0], bq[10][1], pb0, pb1, "640") GLD2(bq[11][0], bq[11][1], pb0, pb1, "704")
        GLD2(bq[12][0], bq[12][1], pb0, pb1, "768") GLD2(bq[13][0], bq[13][1], pb0, pb1, "832")
        GLD2(bq[14][0], bq[14][1], pb0, pb1, "896") GLD2(bq[15][0], bq[15][1], pb0, pb1, "960")
        CONSUME(0, 16, "30")  GLD2(bq[0][0], bq[0][1], qb0, qb1, "0")
        CONSUME(1, 17, "30")  GLD2(bq[1][0], bq[1][1], qb0, qb1, "64")
        CONSUME(2, 18, "30")  GLD2(bq[2][0], bq[2][1], qb0, qb1, "128")
        CONSUME(3, 19, "30")  GLD2(bq[3][0], bq[3][1], qb0, qb1, "192")
        CONSUME(4, 20, "30")  GLD2(bq[4][0], bq[4][1], qb0, qb1, "256")
        CONSUME(5, 21, "30")  GLD2(bq[5][0], bq[5][1], qb0, qb1, "320")
        CONSUME(6, 22, "30")  GLD2(bq[6][0], bq[6][1], qb0, qb1, "384")
        CONSUME(7, 23, "30")  GLD2(bq[7][0], bq[7][1], qb0, qb1, "448")
        CONSUME(8, 24, "30")  GLD2(bq[8][0], bq[8][1], qb0, qb1, "512")
        CONSUME(9, 25, "30")  GLD2(bq[9][0], bq[9][1], qb0, qb1, "576")
        CONSUME(10, 26, "30") GLD2(bq[10][0], bq[10][1], qb0, qb1, "640")
        CONSUME(11, 27, "30") GLD2(bq[11][0], bq[11][1], qb0, qb1, "704")
        CONSUME(12, 28, "30") GLD2(bq[12][0], bq[12][1], qb0, qb1, "768")
        CONSUME(13, 29, "30") GLD2(bq[13][0], bq[13][1], qb0, qb1, "832")
        CONSUME(14, 30, "30") GLD2(bq[14][0], bq[14][1], qb0, qb1, "896")
        CONSUME(15, 31, "30") GLD2(bq[15][0], bq[15][1], qb0, qb1, "960")
        CONSUME(0, 0, "30")   CONSUME(1, 1, "28")   CONSUME(2, 2, "26")  CONSUME(3, 3, "24")
        CONSUME(4, 4, "22")   CONSUME(5, 5, "20")   CONSUME(6, 6, "18")  CONSUME(7, 7, "16")
        CONSUME(8, 8, "14")   CONSUME(9, 9, "12")   CONSUME(10, 10, "10") CONSUME(11, 11, "8")
        CONSUME(12, 12, "6")  CONSUME(13, 13, "4")  CONSUME(14, 14, "2") CONSUME(15, 15, "0")
      }

      // epilogue: c in regs; h -> LDS transpose stage -> replicated stores
      #pragma unroll
      for (int mf = 0; mf < 4; ++mf) {
        #pragma unroll
        for (int nf = 0; nf < 2; ++nf) {
          const float gi = acc[mf][nf][0] + b4m[mf].x;
          const float gf = acc[mf][nf][1] + b4m[mf].y;
          const float gg = acc[mf][nf][2] + b4m[mf].z;
          const float go = acc[mf][nf][3] + b4m[mf].w;
          const float cn = sigm(gf) * c_reg[mf][nf] + sigm(gi) * tanhfast(gg);
          c_reg[mf][nf] = cn;
          stage[(w * 32 + nf * 16 + l15) * 16 + mf * 4 + l4] =
              f2bf(sigm(go) * tanhfast(cn));
        }
      }
      asm volatile("s_waitcnt lgkmcnt(0)" ::: "memory");
      __builtin_amdgcn_sched_barrier(0);
      {
        const s16x8 hvv = *reinterpret_cast<const s16x8*>(
            (const char*)stage + sb * 32 + sh * 16);
        const size_t ho = (size_t)(l * nring + slotP) * NBH
                          + (size_t)sb * HID2 + wgi * 16 + sh * 8;
        for (int r = 0; r <= nrepm; ++r) {
          const unsigned short* ha = hring + (size_t)r * hrepsz + ho;
          asm volatile("global_store_dwordx4 %0, %1, off sc0 sc1"
                       :: "v"(ha), "v"(hvv) : "memory");
        }
      }
      asm volatile("s_waitcnt vmcnt(0)" ::: "memory");
      __syncthreads();
      if (tid == 0) {
        for (int r = 0; r <= nrepm; ++r) {
          const unsigned int* fa = flags + (size_t)r * FREP
                                   + ((size_t)(l * TT + t) << 5) + wgi;
          asm volatile("global_store_dword %0, %1, off sc0 sc1" :: "v"(fa), "v"(1u) : "memory");
        }
      }
    }
  } else {
    // ---------------- projection ----------------
    const int wgp = bid - 160;
    const int rep = wgp & nrepm;
    const unsigned int* fb = flags + (size_t)rep * FREP;
    const int b0 = wgp * 16;
    for (int mf = 0; mf < 2; ++mf)
      for (int kit = 0; kit < 16; ++kit) {
        const s16x8 v = *reinterpret_cast<const s16x8*>(
            Woutb + (size_t)(w * 32 + mf * 16 + l15) * 512 + kit * 32 + l4 * 8);
        *reinterpret_cast<s16x8*>(smem + (((w * 2 + mf) * 16 + kit) << 10) + lane * 16) = v;
      }
    __syncthreads();
    float4 bo[2];
    #pragma unroll
    for (int mf = 0; mf < 2; ++mf)
      bo[mf] = *(const float4*)(boutp + w * 32 + mf * 16 + l4 * 4);

    s16x8 br[16];
    for (int t = 0; t < TT; ++t) {
      pollAll(fb + ((size_t)(4 * TT + t) << 5) + (lane & 31));
      const unsigned short* h4 = hring + (size_t)rep * hrepsz
                                 + (size_t)(4 * nring + (t & ringm)) * NBH;
      const unsigned short* hb = h4 + (size_t)(b0 + l15) * HID2 + l4 * 8;
      GLD1(br[0], hb, "0")    GLD1(br[1], hb, "64")   GLD1(br[2], hb, "128")  GLD1(br[3], hb, "192")
      GLD1(br[4], hb, "256")  GLD1(br[5], hb, "320")  GLD1(br[6], hb, "384")  GLD1(br[7], hb, "448")
      GLD1(br[8], hb, "512")  GLD1(br[9], hb, "576")  GLD1(br[10], hb, "640") GLD1(br[11], hb, "704")
      GLD1(br[12], hb, "768") GLD1(br[13], hb, "832") GLD1(br[14], hb, "896") GLD1(br[15], hb, "960")
      f32x4 acc2[2] = {};
      #define PCON(Q, VM)                                                        \
        {                                                                        \
          BW1(br[Q], VM);                                                        \
          const s16x8 a0 = *reinterpret_cast<const s16x8*>(                      \
              smem + (((w * 2 + 0) * 16 + Q) << 10) + lane * 16);                \
          const s16x8 a1 = *reinterpret_cast<const s16x8*>(                      \
              smem + (((w * 2 + 1) * 16 + Q) << 10) + lane * 16);                \
          acc2[0] = MFM(a0, br[Q], acc2[0]);                                     \
          acc2[1] = MFM(a1, br[Q], acc2[1]);                                     \
        }
      PCON(0, "15")  PCON(1, "14")  PCON(2, "13")  PCON(3, "12")
      PCON(4, "11")  PCON(5, "10")  PCON(6, "9")   PCON(7, "8")
      PCON(8, "7")   PCON(9, "6")   PCON(10, "5")  PCON(11, "4")
      PCON(12, "3")  PCON(13, "2")  PCON(14, "1")  PCON(15, "0")
      #pragma unroll
      for (int mf = 0; mf < 2; ++mf) {
        const int d0 = w * 32 + mf * 16 + l4 * 4;
        float4 r;
        r.x = acc2[mf][0] + bo[mf].x;
        r.y = acc2[mf][1] + bo[mf].y;
        r.z = acc2[mf][2] + bo[mf].z;
        r.w = acc2[mf][3] + bo[mf].w;
        *(float4*)(outp + ((size_t)(b0 + l15) * TT + t) * 128 + d0) = r;
      }
      asm volatile("s_waitcnt vmcnt(0)" ::: "memory");
      __syncthreads();
      if (tid == 0) {
        for (int r = 0; r <= nrepm; ++r) {
          const unsigned int* fa = flags + (size_t)r * FREP
                                   + ((size_t)(5 * TT + t) << 5) + wgp;
          asm volatile("global_store_dword %0, %1, off sc0 sc1" :: "v"(fa), "v"(1u) : "memory");
        }
      }
    }
  }
}

extern "C" void kernel_launch(void* const* d_in, const int* in_sizes, int n_in,
                              void* d_out, int out_size, void* d_ws, size_t ws_size,
                              hipStream_t stream) {
  (void)in_sizes; (void)n_in; (void)out_size;
  const float* x     = (const float*)d_in[0];
  const float* Wih1  = (const float*)d_in[1];
  const float* Whh1  = (const float*)d_in[2];
  const float* bih1  = (const float*)d_in[3];
  const float* bhh1  = (const float*)d_in[4];
  const float* Wih_r = (const float*)d_in[5];
  const float* Whh_r = (const float*)d_in[6];
  const float* bih_r = (const float*)d_in[7];
  const float* bhh_r = (const float*)d_in[8];
  const float* Wout  = (const float*)d_in[9];
  const float* boutp = (const float*)d_in[10];

  char* ws = (char*)d_ws;
  const size_t o_W0   = 0;
  const size_t o_W1   = o_W0 + 2048ull * 640 * 2;
  const size_t o_W2   = o_W1 + 2048ull * 1024 * 2;
  const size_t o_W3   = o_W2 + 2048ull * 1024 * 2;
  const size_t o_W4   = o_W3 + 2048ull * 1024 * 2;
  const size_t o_Wout = o_W4 + 2048ull * 1024 * 2;
  const size_t o_bias = o_Wout + 128ull * 512 * 2;
  const size_t o_ring = o_bias + 5ull * 2048 * 4;

  // deep (4-replica, RING=16) layout
  const size_t hrep16 = 5ull * 16 * NBH;            // elems per replica
  const size_t o_flag4 = o_ring + 4 * hrep16 * 2;
  const size_t need4   = o_flag4 + 4ull * FREP * 4;
  // fallback (1-replica, RING=8)
  const size_t hrep8  = 5ull * 8 * NBH;
  const size_t o_flag1 = o_ring + hrep8 * 2;
  const size_t need1   = o_flag1 + (size_t)FREP * 4;

  const bool deep = (ws_size >= need4);
  const int nrepm = deep ? 3 : 0;
  const int nring = deep ? 16 : 8;
  const size_t hrepsz = deep ? hrep16 : hrep8;
  const size_t o_flag = deep ? o_flag4 : o_flag1;
  const size_t o_end  = deep ? need4 : need1;

  unsigned short* W0b  = (unsigned short*)(ws + o_W0);
  unsigned short* W1b  = (unsigned short*)(ws + o_W1);
  unsigned short* W2b  = (unsigned short*)(ws + o_W2);
  unsigned short* W3b  = (unsigned short*)(ws + o_W3);
  unsigned short* W4b  = (unsigned short*)(ws + o_W4);
  unsigned short* Wob  = (unsigned short*)(ws + o_Wout);
  float*          bias = (float*)(ws + o_bias);
  unsigned short* hrg  = (unsigned short*)(ws + o_ring);
  unsigned int*   flg  = (unsigned int*)(ws + o_flag);

  hipMemsetAsync(ws + o_ring, 0, o_end - o_ring, stream);

  convW<<<1024, 256, 0, stream>>>(Wih1, Whh1, bih1, bhh1, W0b, bias, 128, 512);
  for (int l = 1; l <= 4; ++l) {
    unsigned short* Wd = (l == 1) ? W1b : (l == 2) ? W2b : (l == 3) ? W3b : W4b;
    convW<<<1024, 256, 0, stream>>>(Wih_r + (size_t)(l - 1) * 2048 * 512,
                                    Whh_r + (size_t)(l - 1) * 2048 * 512,
                                    bih_r + (size_t)(l - 1) * 2048,
                                    bhh_r + (size_t)(l - 1) * 2048,
                                    Wd, bias + l * 2048, 512, 512);
  }
  convO<<<64, 256, 0, stream>>>(Wout, Wob);

  hipFuncSetAttribute((const void*)lstm_rep,
                      hipFuncAttributeMaxDynamicSharedMemorySize, 160 * 1024);

  lstm_rep<<<168, 256, 135168, stream>>>(x, W0b, W1b, W2b, W3b, W4b, Wob,
                                         bias, hrg, flg, boutp, (float*)d_out,
                                         nrepm, nring, nring - 1, hrepsz);
}

// Round 11
// 9762.781 us; speedup vs baseline: 2.1196x; 1.2541x over previous
//
#include <hip/hip_runtime.h>

// LSTM_65859028517106 — round 11: k-major h ring (h[kc][b][8]) so every
// bypass B-load is lane-contiguous (8 full 128B lines/instr, was 16 half
// lines) and h stores are 2KB-contiguous. Same math/protocol as r4/r10;
// RING=16, 1-in-4 back-pressure, no replication.

typedef short s16x8 __attribute__((ext_vector_type(8)));
typedef float f32x4 __attribute__((ext_vector_type(4)));

#define NB   128
#define TT   1024
#define HID2 512
#define RING 16
#define RINGM 15
#define NBH  (NB * HID2)
#define STAGE_OFF (128 * 1024)

__device__ __forceinline__ unsigned short f2bf(float f) {
  union { float f; unsigned int u; } c; c.f = f;
  return (unsigned short)((c.u + 0x7fffu + ((c.u >> 16) & 1u)) >> 16);
}
__device__ __forceinline__ float sigm(float x) { return 1.0f / (1.0f + __expf(-x)); }
__device__ __forceinline__ float tanhfast(float x) {
  x = fminf(fmaxf(x, -15.0f), 15.0f);
  const float e = __expf(2.0f * x);
  return (e - 1.0f) / (e + 1.0f);
}

__global__ void convW(const float* __restrict__ Wih, const float* __restrict__ Whh,
                      const float* __restrict__ bih, const float* __restrict__ bhh,
                      unsigned short* __restrict__ Wd, float* __restrict__ biasd,
                      const int Kih, const int Khh) {
  const int K = Kih + Khh;
  const int total = 2048 * K;
  for (int idx = blockIdx.x * blockDim.x + threadIdx.x; idx < total;
       idx += gridDim.x * blockDim.x) {
    const int rp = idx / K;
    const int cc = idx - rp * K;
    const int g = rp & 3, u = rp >> 2;
    const int ro = g * 512 + u;
    const float v = (cc < Kih) ? Wih[ro * Kih + cc] : Whh[ro * Khh + (cc - Kih)];
    Wd[idx] = f2bf(v);
    if (cc == 0) biasd[rp] = bih[ro] + bhh[ro];
  }
}

__global__ void convO(const float* __restrict__ Wout, unsigned short* __restrict__ Wd) {
  for (int idx = blockIdx.x * blockDim.x + threadIdx.x; idx < 128 * 512;
       idx += gridDim.x * blockDim.x)
    Wd[idx] = f2bf(Wout[idx]);
}

// bypass (IC-coherent) ops, pointer-addressed (k-major strides > imm range)
#define GLD2P(D0, D1, P0, P1)                                             \
  asm volatile("global_load_dwordx4 %0, %2, off sc0 sc1\n\t"              \
               "global_load_dwordx4 %1, %3, off sc0 sc1"                  \
               : "=v"(D0), "=v"(D1) : "v"(P0), "v"(P1));
#define GLD1P(D, P)                                                       \
  asm volatile("global_load_dwordx4 %0, %1, off sc0 sc1"                  \
               : "=v"(D) : "v"(P));
#define BWAIT(D0, D1, VM)                                                 \
  asm volatile("s_waitcnt vmcnt(" VM ")" : "+v"(D0), "+v"(D1)::"memory");
#define BW1(D, VM)                                                        \
  asm volatile("s_waitcnt vmcnt(" VM ")" : "+v"(D)::"memory");

#define MFM(A, B, C) __builtin_amdgcn_mfma_f32_16x16x32_bf16(A, B, C, 0, 0, 0)
#define LDSA(MFi, AK) \
  (*reinterpret_cast<const s16x8*>(smem + (((MFi) * nkit + (AK)) << 10) + lane * 16))
#define CONSUME(SLOT, AK, VM)                                                   \
  {                                                                             \
    BWAIT(bq[SLOT][0], bq[SLOT][1], VM);                                        \
    const s16x8 af0 = LDSA(0, AK), af1 = LDSA(1, AK), af2 = LDSA(2, AK),        \
                af3 = LDSA(3, AK);                                              \
    acc[0][0] = MFM(af0, bq[SLOT][0], acc[0][0]);                               \
    acc[0][1] = MFM(af0, bq[SLOT][1], acc[0][1]);                               \
    acc[1][0] = MFM(af1, bq[SLOT][0], acc[1][0]);                               \
    acc[1][1] = MFM(af1, bq[SLOT][1], acc[1][1]);                               \
    acc[2][0] = MFM(af2, bq[SLOT][0], acc[2][0]);                               \
    acc[2][1] = MFM(af2, bq[SLOT][1], acc[2][1]);                               \
    acc[3][0] = MFM(af3, bq[SLOT][0], acc[3][0]);                               \
    acc[3][1] = MFM(af3, bq[SLOT][1], acc[3][1]);                               \
  }

// issue 16 bundles from base BP (bundle j at +j*4096 ushorts = kit stride 8KB)
#define ISSUE16K(BP)                                                            \
  GLD2P(bq[0][0], bq[0][1], (BP), (BP) + 128)                                   \
  GLD2P(bq[1][0], bq[1][1], (BP) + 4096, (BP) + 4224)                           \
  GLD2P(bq[2][0], bq[2][1], (BP) + 8192, (BP) + 8320)                           \
  GLD2P(bq[3][0], bq[3][1], (BP) + 12288, (BP) + 12416)                         \
  GLD2P(bq[4][0], bq[4][1], (BP) + 16384, (BP) + 16512)                         \
  GLD2P(bq[5][0], bq[5][1], (BP) + 20480, (BP) + 20608)                         \
  GLD2P(bq[6][0], bq[6][1], (BP) + 24576, (BP) + 24704)                         \
  GLD2P(bq[7][0], bq[7][1], (BP) + 28672, (BP) + 28800)                         \
  GLD2P(bq[8][0], bq[8][1], (BP) + 32768, (BP) + 32896)                         \
  GLD2P(bq[9][0], bq[9][1], (BP) + 36864, (BP) + 36992)                         \
  GLD2P(bq[10][0], bq[10][1], (BP) + 40960, (BP) + 41088)                       \
  GLD2P(bq[11][0], bq[11][1], (BP) + 45056, (BP) + 45184)                       \
  GLD2P(bq[12][0], bq[12][1], (BP) + 49152, (BP) + 49280)                       \
  GLD2P(bq[13][0], bq[13][1], (BP) + 53248, (BP) + 53376)                       \
  GLD2P(bq[14][0], bq[14][1], (BP) + 57344, (BP) + 57472)                       \
  GLD2P(bq[15][0], bq[15][1], (BP) + 61440, (BP) + 61568)

#define FLG(L, T) (flags + ((size_t)((L) * TT + (T)) << 5))

__global__ __launch_bounds__(256, 1) void lstm_km(
    const float* __restrict__ x,
    const unsigned short* __restrict__ W0, const unsigned short* __restrict__ W1,
    const unsigned short* __restrict__ W2, const unsigned short* __restrict__ W3,
    const unsigned short* __restrict__ W4,
    const unsigned short* __restrict__ Woutb,
    const float* __restrict__ bias,
    unsigned short* __restrict__ hring,   // [5][RING][64 kc][128 b][8]
    unsigned int* __restrict__ flags,     // [6][TT][32]
    const float* __restrict__ boutp,
    float* __restrict__ outp)
{
  extern __shared__ char smem[];
  const int tid = threadIdx.x;
  const int lane = tid & 63;
  const int w = tid >> 6;
  const int l15 = lane & 15;
  const int l4 = lane >> 4;
  const int bid = blockIdx.x;

  auto pollAll = [&](const unsigned int* pa) {
    for (;;) {
      unsigned int v;
      asm volatile("global_load_dword %0, %1, off sc0 sc1\n\ts_waitcnt vmcnt(0)"
                   : "=v"(v) : "v"(pa) : "memory");
      if (__all(v != 0)) break;
      __builtin_amdgcn_s_sleep(1);
    }
  };

  if (bid < 160) {
    const int l = bid >> 5;
    const int wgi = bid & 31;
    const int K = (l == 0) ? 640 : 1024;
    const int nkit = K >> 5;
    const unsigned short* Wg = (l == 0) ? W0 : (l == 1) ? W1 : (l == 2) ? W2
                              : (l == 3) ? W3 : W4;
    const int row0 = wgi * 64;

    // one-time W fragment preload into LDS (row-major W', r4-identical)
    for (int mf = 0; mf < 4; ++mf)
      for (int kit = w; kit < nkit; kit += 4) {
        const s16x8 v = *reinterpret_cast<const s16x8*>(
            Wg + (size_t)(row0 + mf * 16 + l15) * K + kit * 32 + l4 * 8);
        *reinterpret_cast<s16x8*>(smem + ((mf * nkit + kit) << 10) + lane * 16) = v;
      }
    __syncthreads();

    float4 b4m[4];
    #pragma unroll
    for (int mf = 0; mf < 4; ++mf)
      b4m[mf] = *(const float4*)(bias + l * 2048 + row0 + mf * 16 + l4 * 4);

    float c_reg[4][2] = {};
    s16x8 bq[16][2];
    unsigned short* stage = (unsigned short*)(smem + STAGE_OFF);  // [2][128][8]
    const int kcl = lane >> 5;               // writeback: kc-local 0/1
    const int bb = w * 32 + (lane & 31);     // writeback: own-wave batch row

    for (int t = 0; t < TT; ++t) {
      const int slotP = t & RINGM, slotM = (t + RINGM) & RINGM;
      const unsigned short* hin = (l > 0)
          ? hring + (size_t)((l - 1) * RING + slotP) * NBH : nullptr;
      const unsigned short* hown = hring + (size_t)(l * RING + slotM) * NBH;
      unsigned short* hout = hring + (size_t)(l * RING + slotP) * NBH;

      f32x4 acc[4][2] = {};
      s16x8 xb[4][2];

      if (l == 0) {
        #pragma unroll
        for (int kx = 0; kx < 4; ++kx)
          #pragma unroll
          for (int nf = 0; nf < 2; ++nf) {
            const float* xs = x + ((size_t)(w * 32 + nf * 16 + l15) * TT + t) * 128
                              + kx * 32 + l4 * 8;
            const float4 v0 = *(const float4*)xs;
            const float4 v1 = *(const float4*)(xs + 4);
            union { s16x8 v; unsigned short a[8]; } pk;
            pk.a[0] = f2bf(v0.x); pk.a[1] = f2bf(v0.y); pk.a[2] = f2bf(v0.z); pk.a[3] = f2bf(v0.w);
            pk.a[4] = f2bf(v1.x); pk.a[5] = f2bf(v1.y); pk.a[6] = f2bf(v1.z); pk.a[7] = f2bf(v1.w);
            xb[kx][nf] = pk.v;
          }
      }

      // fused poll: lanes 0..31 self(t-1), lanes 32..63 prev(t)
      if (t > 0 || l > 0) {
        const unsigned int* pa;
        if (lane < 32)
          pa = (t > 0) ? FLG(l, t - 1) + lane : FLG(l - 1, t) + lane;
        else
          pa = (l > 0) ? FLG(l - 1, t) + (lane - 32) : FLG(l, t - 1) + (lane - 32);
        pollAll(pa);
      }
      // back-pressure: RING=16, poll 1-in-4 steps at slack 13
      if ((t & 3) == 0 && t >= 16) {
        const unsigned int* pa = (l < 4) ? FLG(l + 1, t - 13) + (lane & 31)
                                         : FLG(5, t - 13) + (lane & 7);
        pollAll(pa);
      }

      // k-major consumer base: addr(kc,b) = (kc*128+b)*8 ushorts;
      // lane needs kc = kit*4 + l4, b = w*32 + nf*16 + l15.
      const unsigned short* hpb = hown + ((size_t)l4 * 128 + w * 32 + l15) * 8;

      if (l == 0) {
        ISSUE16K(hpb)           // bundles j=0..15 = abs kits 4..19 (hown kc j*4+l4)
        #pragma unroll
        for (int kx = 0; kx < 4; ++kx) {
          const s16x8 a0 = LDSA(0, kx), a1 = LDSA(1, kx), a2 = LDSA(2, kx), a3 = LDSA(3, kx);
          acc[0][0] = MFM(a0, xb[kx][0], acc[0][0]); acc[0][1] = MFM(a0, xb[kx][1], acc[0][1]);
          acc[1][0] = MFM(a1, xb[kx][0], acc[1][0]); acc[1][1] = MFM(a1, xb[kx][1], acc[1][1]);
          acc[2][0] = MFM(a2, xb[kx][0], acc[2][0]); acc[2][1] = MFM(a2, xb[kx][1], acc[2][1]);
          acc[3][0] = MFM(a3, xb[kx][0], acc[3][0]); acc[3][1] = MFM(a3, xb[kx][1], acc[3][1]);
        }
        CONSUME(0, 4, "30")   CONSUME(1, 5, "28")   CONSUME(2, 6, "26")   CONSUME(3, 7, "24")
        CONSUME(4, 8, "22")   CONSUME(5, 9, "20")   CONSUME(6, 10, "18")  CONSUME(7, 11, "16")
        CONSUME(8, 12, "14")  CONSUME(9, 13, "12")  CONSUME(10, 14, "10") CONSUME(11, 15, "8")
        CONSUME(12, 16, "6")  CONSUME(13, 17, "4")  CONSUME(14, 18, "2")  CONSUME(15, 19, "0")
      } else {
        const unsigned short* qpb = hin + ((size_t)l4 * 128 + w * 32 + l15) * 8;
        ISSUE16K(hpb)           // bundles = abs kits 16..31 (hown)
        CONSUME(0, 16, "30")  GLD2P(bq[0][0], bq[0][1], qpb, qpb + 128)
        CONSUME(1, 17, "30")  GLD2P(bq[1][0], bq[1][1], qpb + 4096, qpb + 4224)
        CONSUME(2, 18, "30")  GLD2P(bq[2][0], bq[2][1], qpb + 8192, qpb + 8320)
        CONSUME(3, 19, "30")  GLD2P(bq[3][0], bq[3][1], qpb + 12288, qpb + 12416)
        CONSUME(4, 20, "30")  GLD2P(bq[4][0], bq[4][1], qpb + 16384, qpb + 16512)
        CONSUME(5, 21, "30")  GLD2P(bq[5][0], bq[5][1], qpb + 20480, qpb + 20608)
        CONSUME(6, 22, "30")  GLD2P(bq[6][0], bq[6][1], qpb + 24576, qpb + 24704)
        CONSUME(7, 23, "30")  GLD2P(bq[7][0], bq[7][1], qpb + 28672, qpb + 28800)
        CONSUME(8, 24, "30")  GLD2P(bq[8][0], bq[8][1], qpb + 32768, qpb + 32896)
        CONSUME(9, 25, "30")  GLD2P(bq[9][0], bq[9][1], qpb + 36864, qpb + 36992)
        CONSUME(10, 26, "30") GLD2P(bq[10][0], bq[10][1], qpb + 40960, qpb + 41088)
        CONSUME(11, 27, "30") GLD2P(bq[11][0], bq[11][1], qpb + 45056, qpb + 45184)
        CONSUME(12, 28, "30") GLD2P(bq[12][0], bq[12][1], qpb + 49152, qpb + 49280)
        CONSUME(13, 29, "30") GLD2P(bq[13][0], bq[13][1], qpb + 53248, qpb + 53376)
        CONSUME(14, 30, "30") GLD2P(bq[14][0], bq[14][1], qpb + 57344, qpb + 57472)
        CONSUME(15, 31, "30") GLD2P(bq[15][0], bq[15][1], qpb + 61440, qpb + 61568)
        CONSUME(0, 0, "30")   CONSUME(1, 1, "28")   CONSUME(2, 2, "26")  CONSUME(3, 3, "24")
        CONSUME(4, 4, "22")   CONSUME(5, 5, "20")   CONSUME(6, 6, "18")  CONSUME(7, 7, "16")
        CONSUME(8, 8, "14")   CONSUME(9, 9, "12")   CONSUME(10, 10, "10") CONSUME(11, 11, "8")
        CONSUME(12, 12, "6")  CONSUME(13, 13, "4")  CONSUME(14, 14, "2") CONSUME(15, 15, "0")
      }

      // epilogue: c in regs; h -> LDS k-major stage [2][128][8] -> one
      // contiguous dwordx4 per lane (2KB runs, full lines).
      // unit u = wgi*16 + mf*4 + l4 -> kc = wgi*2 + (mf>>1), e = (mf&1)*4 + l4.
      #pragma unroll
      for (int mf = 0; mf < 4; ++mf) {
        #pragma unroll
        for (int nf = 0; nf < 2; ++nf) {
          const float gi = acc[mf][nf][0] + b4m[mf].x;
          const float gf = acc[mf][nf][1] + b4m[mf].y;
          const float gg = acc[mf][nf][2] + b4m[mf].z;
          const float go = acc[mf][nf][3] + b4m[mf].w;
          const float cn = sigm(gf) * c_reg[mf][nf] + sigm(gi) * tanhfast(gg);
          c_reg[mf][nf] = cn;
          stage[((mf >> 1) * 128 + (w * 32 + nf * 16 + l15)) * 8 + (mf & 1) * 4 + l4] =
              f2bf(sigm(go) * tanhfast(cn));
        }
      }
      asm volatile("s_waitcnt lgkmcnt(0)" ::: "memory");
      __builtin_amdgcn_sched_barrier(0);
      {
        const s16x8 hvv = *reinterpret_cast<const s16x8*>(
            stage + ((size_t)kcl * 128 + bb) * 8);
        const unsigned short* ha = hout + ((size_t)(wgi * 2 + kcl) * 128 + bb) * 8;
        asm volatile("global_store_dwordx4 %0, %1, off sc0 sc1"
                     :: "v"(ha), "v"(hvv) : "memory");
      }
      asm volatile("s_waitcnt vmcnt(0)" ::: "memory");
      __syncthreads();
      if (tid == 0) {
        const unsigned int* fa = FLG(l, t) + wgi;
        asm volatile("global_store_dword %0, %1, off sc0 sc1" :: "v"(fa), "v"(1u) : "memory");
      }
    }
  } else {
    // ---------------- projection (k-major h4 reads) ----------------
    const int wgp = bid - 160;
    const int b0 = wgp * 16;
    for (int mf = 0; mf < 2; ++mf)
      for (int kit = 0; kit < 16; ++kit) {
        const s16x8 v = *reinterpret_cast<const s16x8*>(
            Woutb + (size_t)(w * 32 + mf * 16 + l15) * 512 + kit * 32 + l4 * 8);
        *reinterpret_cast<s16x8*>(smem + (((w * 2 + mf) * 16 + kit) << 10) + lane * 16) = v;
      }
    __syncthreads();
    float4 bo[2];
    #pragma unroll
    for (int mf = 0; mf < 2; ++mf)
      bo[mf] = *(const float4*)(boutp + w * 32 + mf * 16 + l4 * 4);

    s16x8 brp[16];
    for (int t = 0; t < TT; ++t) {
      pollAll(FLG(4, t) + (lane & 31));
      const unsigned short* h4 = hring + (size_t)(4 * RING + (t & RINGM)) * NBH;
      const unsigned short* hbK = h4 + ((size_t)l4 * 128 + b0 + l15) * 8;
      GLD1P(brp[0], hbK)           GLD1P(brp[1], hbK + 4096)
      GLD1P(brp[2], hbK + 8192)    GLD1P(brp[3], hbK + 12288)
      GLD1P(brp[4], hbK + 16384)   GLD1P(brp[5], hbK + 20480)
      GLD1P(brp[6], hbK + 24576)   GLD1P(brp[7], hbK + 28672)
      GLD1P(brp[8], hbK + 32768)   GLD1P(brp[9], hbK + 36864)
      GLD1P(brp[10], hbK + 40960)  GLD1P(brp[11], hbK + 45056)
      GLD1P(brp[12], hbK + 49152)  GLD1P(brp[13], hbK + 53248)
      GLD1P(brp[14], hbK + 57344)  GLD1P(brp[15], hbK + 61440)
      f32x4 acc2[2] = {};
      #define PCON(Q, VM)                                                        \
        {                                                                        \
          BW1(brp[Q], VM);                                                       \
          const s16x8 a0 = *reinterpret_cast<const s16x8*>(                      \
              smem + (((w * 2 + 0) * 16 + Q) << 10) + lane * 16);                \
          const s16x8 a1 = *reinterpret_cast<const s16x8*>(                      \
              smem + (((w * 2 + 1) * 16 + Q) << 10) + lane * 16);                \
          acc2[0] = MFM(a0, brp[Q], acc2[0]);                                    \
          acc2[1] = MFM(a1, brp[Q], acc2[1]);                                    \
        }
      PCON(0, "15")  PCON(1, "14")  PCON(2, "13")  PCON(3, "12")
      PCON(4, "11")  PCON(5, "10")  PCON(6, "9")   PCON(7, "8")
      PCON(8, "7")   PCON(9, "6")   PCON(10, "5")  PCON(11, "4")
      PCON(12, "3")  PCON(13, "2")  PCON(14, "1")  PCON(15, "0")
      #pragma unroll
      for (int mf = 0; mf < 2; ++mf) {
        const int d0 = w * 32 + mf * 16 + l4 * 4;
        float4 r;
        r.x = acc2[mf][0] + bo[mf].x;
        r.y = acc2[mf][1] + bo[mf].y;
        r.z = acc2[mf][2] + bo[mf].z;
        r.w = acc2[mf][3] + bo[mf].w;
        *(float4*)(outp + ((size_t)(b0 + l15) * TT + t) * 128 + d0) = r;
      }
      asm volatile("s_waitcnt vmcnt(0)" ::: "memory");
      __syncthreads();
      if (tid == 0) {
        const unsigned int* fa = FLG(5, t) + wgp;
        asm volatile("global_store_dword %0, %1, off sc0 sc1" :: "v"(fa), "v"(1u) : "memory");
      }
    }
  }
}

extern "C" void kernel_launch(void* const* d_in, const int* in_sizes, int n_in,
                              void* d_out, int out_size, void* d_ws, size_t ws_size,
                              hipStream_t stream) {
  (void)in_sizes; (void)n_in; (void)out_size; (void)ws_size;
  const float* x     = (const float*)d_in[0];
  const float* Wih1  = (const float*)d_in[1];
  const float* Whh1  = (const float*)d_in[2];
  const float* bih1  = (const float*)d_in[3];
  const float* bhh1  = (const float*)d_in[4];
  const float* Wih_r = (const float*)d_in[5];
  const float* Whh_r = (const float*)d_in[6];
  const float* bih_r = (const float*)d_in[7];
  const float* bhh_r = (const float*)d_in[8];
  const float* Wout  = (const float*)d_in[9];
  const float* boutp = (const float*)d_in[10];

  char* ws = (char*)d_ws;
  const size_t o_W0   = 0;
  const size_t o_W1   = o_W0 + 2048ull * 640 * 2;
  const size_t o_W2   = o_W1 + 2048ull * 1024 * 2;
  const size_t o_W3   = o_W2 + 2048ull * 1024 * 2;
  const size_t o_W4   = o_W3 + 2048ull * 1024 * 2;
  const size_t o_Wout = o_W4 + 2048ull * 1024 * 2;
  const size_t o_bias = o_Wout + 128ull * 512 * 2;
  const size_t o_ring = o_bias + 5ull * 2048 * 4;
  const size_t o_flag = o_ring + 5ull * RING * NBH * 2;
  const size_t o_end  = o_flag + 6ull * TT * 32 * 4;

  unsigned short* W0b  = (unsigned short*)(ws + o_W0);
  unsigned short* W1b  = (unsigned short*)(ws + o_W1);
  unsigned short* W2b  = (unsigned short*)(ws + o_W2);
  unsigned short* W3b  = (unsigned short*)(ws + o_W3);
  unsigned short* W4b  = (unsigned short*)(ws + o_W4);
  unsigned short* Wob  = (unsigned short*)(ws + o_Wout);
  float*          bias = (float*)(ws + o_bias);
  unsigned short* hrg  = (unsigned short*)(ws + o_ring);
  unsigned int*   flg  = (unsigned int*)(ws + o_flag);

  hipMemsetAsync(ws + o_ring, 0, o_end - o_ring, stream);

  convW<<<1024, 256, 0, stream>>>(Wih1, Whh1, bih1, bhh1, W0b, bias, 128, 512);
  for (int l = 1; l <= 4; ++l) {
    unsigned short* Wd = (l == 1) ? W1b : (l == 2) ? W2b : (l == 3) ? W3b : W4b;
    convW<<<1024, 256, 0, stream>>>(Wih_r + (size_t)(l - 1) * 2048 * 512,
                                    Whh_r + (size_t)(l - 1) * 2048 * 512,
                                    bih_r + (size_t)(l - 1) * 2048,
                                    bhh_r + (size_t)(l - 1) * 2048,
                                    Wd, bias + l * 2048, 512, 512);
  }
  convO<<<64, 256, 0, stream>>>(Wout, Wob);

  hipFuncSetAttribute((const void*)lstm_km,
                      hipFuncAttributeMaxDynamicSharedMemorySize, 160 * 1024);

  lstm_km<<<168, 256, 135168, stream>>>(x, W0b, W1b, W2b, W3b, W4b, Wob,
                                        bias, hrg, flg, boutp, (float*)d_out);
}